// Round 1
// baseline (335.095 us; speedup 1.0000x reference)
//
#include <hip/hip_runtime.h>
#include <hip/hip_bf16.h>

// Pairwise Euclidean distance: out[i][j] = ||x_i - y_j||,
// x: [4096, 256] fp32, y: [16384, 256] fp32, out: [4096, 16384] fp32.
// Strategy: d2 = x2 + y2 - 2*<x,y>; cross term via bf16 MFMA, norms in fp32.

using bf16x8  = __attribute__((ext_vector_type(8))) short;
using f32x4   = __attribute__((ext_vector_type(4))) float;
using ushort8 = __attribute__((ext_vector_type(8))) unsigned short;

constexpr int NXR = 4096;    // rows of x
constexpr int NYR = 16384;   // rows of y
constexpr int DD  = 256;     // feature dim

constexpr int BM = 128;      // x-rows per block
constexpr int BN = 128;      // y-rows per block
constexpr int BK = 128;      // K slice per stage
constexpr int PK = BK + 8;   // padded LDS row (ushorts): 272 B = 68 dwords -> 2-way bank alias (free)

__device__ inline unsigned short f2bf(float f) {
    unsigned int b = __float_as_uint(f);
    b += 0x7FFFu + ((b >> 16) & 1u);   // RNE
    return (unsigned short)(b >> 16);
}

// ---------------- norms kernel: ws[0..4096) = ||x_i||^2, ws[4096..20480) = ||y_j||^2
__global__ __launch_bounds__(256) void norms_kernel(const float* __restrict__ x,
                                                    const float* __restrict__ y,
                                                    float* __restrict__ ws) {
    const int row  = blockIdx.x * 4 + (threadIdx.x >> 6);   // one wave per row
    const int lane = threadIdx.x & 63;
    const float* src = (row < NXR) ? (x + (size_t)row * DD)
                                   : (y + (size_t)(row - NXR) * DD);
    float4 v = *(const float4*)(src + lane * 4);            // 64 lanes x 4 floats = 256
    float s = v.x * v.x + v.y * v.y + v.z * v.z + v.w * v.w;
    #pragma unroll
    for (int off = 32; off > 0; off >>= 1) s += __shfl_down(s, off, 64);
    if (lane == 0) ws[row] = s;
}

// ---------------- main distance kernel
__global__ __launch_bounds__(512) void dist_kernel(const float* __restrict__ x,
                                                   const float* __restrict__ y,
                                                   const float* __restrict__ xn,
                                                   const float* __restrict__ yn,
                                                   float* __restrict__ out) {
    __shared__ unsigned short lA[BM * PK];
    __shared__ unsigned short lB[BN * PK];

    const int bm = blockIdx.x;          // 0..31
    const int bn = blockIdx.y;          // 0..127
    const int tid  = threadIdx.x;
    const int wave = tid >> 6;          // 0..7
    const int lane = tid & 63;
    const int wm   = wave & 1;          // 2 waves in M
    const int wn   = wave >> 1;         // 4 waves in N
    const int quad = lane >> 4;
    const int l15  = lane & 15;

    f32x4 acc[4][2];
    #pragma unroll
    for (int i = 0; i < 4; ++i)
        #pragma unroll
        for (int j = 0; j < 2; ++j)
            acc[i][j] = f32x4{0.f, 0.f, 0.f, 0.f};

    const int sc  = (tid & 15) * 8;     // float col within k-slice
    const int sr0 = tid >> 4;           // 0..31

    #pragma unroll
    for (int kt = 0; kt < 2; ++kt) {
        if (kt) __syncthreads();
        // ---- stage: fp32 -> bf16 into LDS (A and B tiles, 128x128 each)
        #pragma unroll
        for (int p = 0; p < 4; ++p) {
            const int r = p * 32 + sr0;
            const float* sa = x + (size_t)(bm * BM + r) * DD + kt * BK + sc;
            float4 a0 = *(const float4*)sa;
            float4 a1 = *(const float4*)(sa + 4);
            ushort8 ua = { f2bf(a0.x), f2bf(a0.y), f2bf(a0.z), f2bf(a0.w),
                           f2bf(a1.x), f2bf(a1.y), f2bf(a1.z), f2bf(a1.w) };
            *(ushort8*)&lA[r * PK + sc] = ua;
            const float* sb = y + (size_t)(bn * BN + r) * DD + kt * BK + sc;
            float4 b0 = *(const float4*)sb;
            float4 b1 = *(const float4*)(sb + 4);
            ushort8 ub = { f2bf(b0.x), f2bf(b0.y), f2bf(b0.z), f2bf(b0.w),
                           f2bf(b1.x), f2bf(b1.y), f2bf(b1.z), f2bf(b1.w) };
            *(ushort8*)&lB[r * PK + sc] = ub;
        }
        __syncthreads();
        // ---- compute: 4 K-steps of 16x16x32 MFMA
        const int ar = (wm * 64 + l15) * PK;
        const int br = (wn * 32 + l15) * PK;
        #pragma unroll
        for (int kk = 0; kk < 4; ++kk) {
            const int k = kk * 32 + quad * 8;
            bf16x8 av[4], bv[2];
            #pragma unroll
            for (int i = 0; i < 4; ++i)
                av[i] = *(const bf16x8*)&lA[ar + i * 16 * PK + k];
            #pragma unroll
            for (int j = 0; j < 2; ++j)
                bv[j] = *(const bf16x8*)&lB[br + j * 16 * PK + k];
            #pragma unroll
            for (int i = 0; i < 4; ++i)
                #pragma unroll
                for (int j = 0; j < 2; ++j)
                    acc[i][j] = __builtin_amdgcn_mfma_f32_16x16x32_bf16(
                        av[i], bv[j], acc[i][j], 0, 0, 0);
        }
    }

    // ---- epilogue: d = sqrt(max(x2 + y2 - 2*xy, 0))
    const int gr_base = bm * BM + wm * 64;
    const int gc_base = bn * BN + wn * 32;
    #pragma unroll
    for (int i = 0; i < 4; ++i) {
        const int gr0 = gr_base + i * 16 + quad * 4;
        #pragma unroll
        for (int r = 0; r < 4; ++r) {
            const float xv = xn[gr0 + r];
            const size_t ro = (size_t)(gr0 + r) * NYR;
            #pragma unroll
            for (int j = 0; j < 2; ++j) {
                const int gc = gc_base + j * 16 + l15;
                const float d2 = xv + yn[gc] - 2.0f * acc[i][j][r];
                out[ro + gc] = sqrtf(fmaxf(d2, 0.0f));
            }
        }
    }
}

extern "C" void kernel_launch(void* const* d_in, const int* in_sizes, int n_in,
                              void* d_out, int out_size, void* d_ws, size_t ws_size,
                              hipStream_t stream) {
    const float* x = (const float*)d_in[0];
    const float* y = (const float*)d_in[1];
    float* ws  = (float*)d_ws;           // [0,4096): x2, [4096,20480): y2
    float* out = (float*)d_out;

    norms_kernel<<<(NXR + NYR) / 4, 256, 0, stream>>>(x, y, ws);
    dist_kernel<<<dim3(NXR / BM, NYR / BN), 512, 0, stream>>>(x, y, ws, ws + NXR, out);
}